// Round 8
// baseline (308.648 us; speedup 1.0000x reference)
//
#include <hip/hip_runtime.h>
#include <hip/hip_bf16.h>

#define SEQ   2048
#define BATCH 2
#define NROWS 4096
#define DM    1024
#define NHEAD 16
#define DH    64
#define QP    512
#define KVP   1024
#define CH    4      // key-tiles (of 64) per flash chunk

typedef unsigned short us;
typedef ushort4 us4;
using bf16x8 = __attribute__((ext_vector_type(8))) __bf16;
using f32x4  = __attribute__((ext_vector_type(4))) float;

__device__ __forceinline__ us f2bf(float f) {
  union { float f; unsigned u; } c; c.f = f;
  return (us)((c.u + 0x8000u) >> 16);    // add-round: <=1 ULP, 2 VALU
}
__device__ __forceinline__ float bf2f(us u) {
  union { unsigned u32; float f; } cv;
  cv.u32 = ((unsigned)u) << 16;
  return cv.f;
}
__device__ __forceinline__ float loadp(const void* p, long i, int isbf) {
  return isbf ? bf2f(((const us*)p)[i]) : ((const float*)p)[i];
}
__device__ __forceinline__ void async16(const void* g, void* l) {
  __builtin_amdgcn_global_load_lds((__attribute__((address_space(1))) void*)g,
                                   (__attribute__((address_space(3))) void*)l,
                                   16, 0, 0);
}

// ----------------------------------- dtype probe + zero small atomic buffers
__global__ void detect_dtype(const us* __restrict__ xu, int* __restrict__ flag,
                             float4* __restrict__ zsmall, int nz4) {
  __shared__ int red[256];
  const int tid = threadIdx.x;
  const float4 z = {0.f, 0.f, 0.f, 0.f};
  for (int i = tid; i < nz4; i += 256) zsmall[i] = z;
  int cnt = 0;
  for (int i = tid; i < 4096; i += 256) {
    const int e = (xu[i] >> 7) & 0xff;
    if (e == 0 || (e >= 100 && e <= 134)) cnt++;
  }
  red[tid] = cnt;
  __syncthreads();
  for (int s = 128; s; s >>= 1) {
    if (tid < s) red[tid] += red[tid + s];
    __syncthreads();
  }
  if (tid == 0) *flag = (red[0] >= 3900) ? 1 : 0;
}

// stage0 grid layout: [0,48) u/c columns; [48,5168) weight prep;
// [5168,6192) zero Oacc/Lacc; [6192,10288) dual-LN of x.
struct TD { const void* in; us* out; int R, C, nt, trans;
            const void* g; const void* b; float* u; float* c; };

__global__ __launch_bounds__(256) void stage0(
    TD t0, TD t1, TD t2, TD t3, TD t4,
    float4* __restrict__ zp, int n4,
    const void* __restrict__ xin,
    const void* __restrict__ g1, const void* __restrict__ b1,
    const void* __restrict__ g2, const void* __restrict__ b2,
    us* __restrict__ out1, us* __restrict__ out2,
    const int* __restrict__ flag)
{
  __shared__ us tile[32][33];
  __shared__ float red[8];
  __shared__ float musd[2];
  __shared__ float ucred[2][4][64];
  const int tid = threadIdx.x;
  const int isbf = *flag;
  int lin = blockIdx.x;

  if (lin < 48) {                                    // ---- u/c fold vectors
    // u[n] = sum_c g[c] W[c][n]; c[n] = sum_c b[c] W[c][n]. 64 cols/block,
    // 4-way split over c, coalesced W loads, LDS reduce.
    TD t = (lin < 16) ? t1 : t3;
    const int blk = (lin < 16) ? lin : lin - 16;
    const int Cr = t.R;              // LN dim (rows of W)
    const int Nc = t.C;              // output cols
    const int colx = tid & 63, cseg = tid >> 6;
    const int col = blk * 64 + colx;
    const int rows = Cr >> 2;
    const int r0 = cseg * rows;
    float usum = 0.f, csum = 0.f;
    for (int cc = 0; cc < rows; cc += 8) {
#pragma unroll
      for (int k = 0; k < 8; k++) {
        const long rr = r0 + cc + k;
        const float w = loadp(t.in, rr * Nc + col, isbf);
        usum += loadp(t.g, rr, isbf) * w;
        csum += loadp(t.b, rr, isbf) * w;
      }
    }
    ucred[0][cseg][colx] = usum;
    ucred[1][cseg][colx] = csum;
    __syncthreads();
    if (tid < 64)
      t.u[blk * 64 + tid] = ucred[0][0][tid] + ucred[0][1][tid] + ucred[0][2][tid] + ucred[0][3][tid];
    else if (tid < 128) {
      const int tt = tid - 64;
      t.c[blk * 64 + tt] = ucred[1][0][tt] + ucred[1][1][tt] + ucred[1][2][tt] + ucred[1][3][tt];
    }
    return;
  }
  lin -= 48;
  if (lin < 5120) {                                  // ---- weight prep
    TD t = t0;
    if (lin >= t.nt) { lin -= t.nt; t = t1;
      if (lin >= t.nt) { lin -= t.nt; t = t2;
        if (lin >= t.nt) { lin -= t.nt; t = t3;
          if (lin >= t.nt) { lin -= t.nt; t = t4; } } } }
    const int ntx = t.C >> 5;
    const int by = lin / ntx, bx = lin - by * ntx;
    const int tx = tid & 31, ty = tid >> 5;
    const long r0 = (long)by * 32, c0 = (long)bx * 32;
    if (t.trans) {
#pragma unroll
      for (int i = 0; i < 32; i += 8)
        tile[ty + i][tx] = isbf ? ((const us*)t.in)[(r0 + ty + i) * t.C + c0 + tx]
                                : f2bf(((const float*)t.in)[(r0 + ty + i) * t.C + c0 + tx]);
      __syncthreads();
      if (t.g) {
        const float gw = loadp(t.g, r0 + tx, isbf);   // this lane's LN-dim index
#pragma unroll
        for (int i = 0; i < 32; i += 8)
          t.out[(c0 + ty + i) * t.R + r0 + tx] = f2bf(bf2f(tile[tx][ty + i]) * gw);
      } else {
#pragma unroll
        for (int i = 0; i < 32; i += 8)
          t.out[(c0 + ty + i) * t.R + r0 + tx] = tile[tx][ty + i];
      }
    } else {
#pragma unroll
      for (int i = 0; i < 32; i += 8)
        t.out[(r0 + ty + i) * t.C + c0 + tx] =
            isbf ? ((const us*)t.in)[(r0 + ty + i) * t.C + c0 + tx]
                 : f2bf(((const float*)t.in)[(r0 + ty + i) * t.C + c0 + tx]);
    }
    return;
  }
  if (lin < 6144) {                                  // ---- zero Oacc/Lacc
    const float4 z = {0.f, 0.f, 0.f, 0.f};
    for (int i = (lin - 5120) * 256 + tid; i < n4; i += 1024 * 256) zp[i] = z;
    return;
  }
  // ---- dual LayerNorm row of x
  const long row = lin - 6144;
  float v[4];
  float s = 0.f, s2 = 0.f;
#pragma unroll
  for (int i = 0; i < 4; i++) {
    const long c = tid + i * 256;
    const float t = loadp(xin, row * 1024 + c, isbf);
    v[i] = t; s += t; s2 += t * t;
  }
#pragma unroll
  for (int off = 32; off > 0; off >>= 1) {
    s  += __shfl_down(s,  off);
    s2 += __shfl_down(s2, off);
  }
  const int wave = tid >> 6, lane = tid & 63;
  if (lane == 0) { red[wave] = s; red[4 + wave] = s2; }
  __syncthreads();
  if (tid == 0) {
    const float ts = red[0] + red[1] + red[2] + red[3];
    const float t2 = red[4] + red[5] + red[6] + red[7];
    const float mu = ts * (1.f / 1024.f);
    const float var = t2 * (1.f / 1024.f) - mu * mu;
    musd[0] = mu; musd[1] = rsqrtf(var + 1e-5f);
  }
  __syncthreads();
  const float mu = musd[0], rs = musd[1];
#pragma unroll
  for (int i = 0; i < 4; i++) {
    const long c = tid + i * 256;
    const float nrm = (v[i] - mu) * rs;
    out1[row * 1024 + c] = f2bf(nrm * loadp(g1, c, isbf) + loadp(b1, c, isbf));
    out2[row * 1024 + c] = f2bf(nrm * loadp(g2, c, isbf) + loadp(b2, c, isbf));
  }
}

// ------------------------------------------------------------------ GEMM C = A @ B
// 64x128 tile (M-split doubles block count vs 128^2 -> occupancy for small
// grids), BK=64 as two 32-slices. A [M,K] bf16, Bt [N,K] bf16, C [M,N].
// omode: 1 bf16; 2 bf16 iff *flag else fp32; 4 bf16 + row stats atomics;
//        5 LN-fold epilogue; 6 LN-fold + kv split (K->C stride 1024, V->C2^T).
struct GD { const us* A; const us* Bt; void* C; int N, K, nxs; float scale; int omode;
            float* S1; float* S2; const float* u; const float* cv; us* C2; };

__global__ __launch_bounds__(256) void gemm_mt(GD g0, GD g1, int nb0,
                                               const int* __restrict__ flag) {
  __shared__ us As[2][64 * 32];
  __shared__ us Bs[2][128 * 32];
  GD g;
  int lin = blockIdx.x;
  if (lin < nb0) g = g0; else { g = g1; lin -= nb0; }
  const int by = lin >> g.nxs;
  const int bx = lin - (by << g.nxs);
  const int N = g.N, K = g.K;

  const int tid  = threadIdx.x;
  const int lane = tid & 63;
  const int wave = tid >> 6;
  const int n16  = lane & 15;
  const int quad = lane >> 4;
  const long m0 = (long)by * 64;
  const long n0 = (long)bx * 128;
  const int wm = (wave >> 1) * 32;
  const int wn = (wave & 1) * 64;

  const f32x4 zero = {0.f, 0.f, 0.f, 0.f};
  f32x4 acc[2][4];
#pragma unroll
  for (int i = 0; i < 2; i++)
#pragma unroll
    for (int j = 0; j < 4; j++) acc[i][j] = zero;

  const int srow = tid >> 2;           // 0..63
  const int scol = (tid & 3) * 8;
  const us* Ag  = g.A  + (m0 + srow) * K + scol;
  const us* Bg0 = g.Bt + (n0 + srow) * K + scol;
  const us* Bg1 = g.Bt + (n0 + 64 + srow) * K + scol;
  const int lds_off = srow * 32 + scol;

  for (int k0 = 0; k0 < K; k0 += 64) {
#pragma unroll
    for (int s = 0; s < 2; s++) {
      const int ks = k0 + s * 32;
      async16(Ag  + ks, As[s] + lds_off);
      async16(Bg0 + ks, Bs[s] + lds_off);
      async16(Bg1 + ks, Bs[s] + 2048 + lds_off);
    }
    __syncthreads();
#pragma unroll
    for (int s = 0; s < 2; s++) {
      bf16x8 af[2], bfv[4];
#pragma unroll
      for (int i = 0; i < 2; i++)
        af[i] = *(const bf16x8*)(As[s] + (wm + i * 16 + n16) * 32 + quad * 8);
#pragma unroll
      for (int j = 0; j < 4; j++)
        bfv[j] = *(const bf16x8*)(Bs[s] + (wn + j * 16 + n16) * 32 + quad * 8);
#pragma unroll
      for (int i = 0; i < 2; i++)
#pragma unroll
        for (int j = 0; j < 4; j++)
          acc[i][j] = __builtin_amdgcn_mfma_f32_16x16x32_bf16(af[i], bfv[j], acc[i][j], 0, 0, 0);
    }
    __syncthreads();
  }

  const int om = g.omode;
  us* Cb = (us*)g.C;

  if (om == 4) {
    float s1a[2][4], s2a[2][4];
#pragma unroll
    for (int i = 0; i < 2; i++)
#pragma unroll
      for (int r = 0; r < 4; r++) { s1a[i][r] = 0.f; s2a[i][r] = 0.f; }
#pragma unroll
    for (int i = 0; i < 2; i++) {
      const long row = m0 + wm + i * 16 + quad * 4;
#pragma unroll
      for (int j = 0; j < 4; j++) {
        const long col = n0 + wn + j * 16 + n16;
#pragma unroll
        for (int r = 0; r < 4; r++) {
          const float v = acc[i][j][r] * g.scale;
          Cb[(row + r) * N + col] = f2bf(v);
          s1a[i][r] += v;
          s2a[i][r] += v * v;
        }
      }
    }
#pragma unroll
    for (int i = 0; i < 2; i++)
#pragma unroll
      for (int r = 0; r < 4; r++) {
        float a = s1a[i][r], b = s2a[i][r];
#pragma unroll
        for (int off = 1; off < 16; off <<= 1) {
          a += __shfl_xor(a, off);
          b += __shfl_xor(b, off);
        }
        if (n16 == 0) {
          const long row = m0 + wm + i * 16 + quad * 4 + r;
          atomicAdd(&g.S1[row], a);
          atomicAdd(&g.S2[row], b);
        }
      }
    return;
  }

  if (om == 5 || om == 6) {
    const float invK = 1.f / (float)K;
    float rsr[2][4], mur[2][4];
#pragma unroll
    for (int i = 0; i < 2; i++) {
      const long row = m0 + wm + i * 16 + quad * 4;
#pragma unroll
      for (int r = 0; r < 4; r++) {
        const float s1 = g.S1[row + r];
        const float s2 = g.S2[row + r];
        const float mu = s1 * invK;
        const float var = s2 * invK - mu * mu;
        const float rs = rsqrtf(var + 1e-5f);
        rsr[i][r] = rs;
        mur[i][r] = mu * rs;
      }
    }
    const bool vhalf = (om == 6) && (n0 >= 1024);
#pragma unroll
    for (int i = 0; i < 2; i++) {
      const long rowb = m0 + wm + i * 16 + quad * 4;
#pragma unroll
      for (int j = 0; j < 4; j++) {
        const long col = n0 + wn + j * 16 + n16;
        const float uu = g.u[col];
        const float cc = g.cv[col];
        if (!vhalf) {
          const int nst = (om == 6) ? 1024 : N;
#pragma unroll
          for (int r = 0; r < 4; r++) {
            const float v = g.scale * (rsr[i][r] * acc[i][j][r] - mur[i][r] * uu + cc);
            Cb[(rowb + r) * nst + col] = f2bf(v);
          }
        } else {
          const int bbq = (int)(rowb >> 11);
          const int key = (int)(rowb & 2047);
          const int dimg = (int)col - 1024;
          us4 pk;
          pk.x = f2bf(g.scale * (rsr[i][0] * acc[i][j][0] - mur[i][0] * uu + cc));
          pk.y = f2bf(g.scale * (rsr[i][1] * acc[i][j][1] - mur[i][1] * uu + cc));
          pk.z = f2bf(g.scale * (rsr[i][2] * acc[i][j][2] - mur[i][2] * uu + cc));
          pk.w = f2bf(g.scale * (rsr[i][3] * acc[i][j][3] - mur[i][3] * uu + cc));
          *(us4*)(g.C2 + ((long)(bbq * 1024 + dimg)) * 2048 + key) = pk;
        }
      }
    }
    return;
  }

  const bool obf = (om == 1) || (om == 2 && *flag != 0);
  float* Cf = (float*)g.C;
#pragma unroll
  for (int i = 0; i < 2; i++) {
    const long row = m0 + wm + i * 16 + quad * 4;
#pragma unroll
    for (int j = 0; j < 4; j++) {
      const long col = n0 + wn + j * 16 + n16;
#pragma unroll
      for (int r = 0; r < 4; r++) {
        const float v = acc[i][j][r] * g.scale;
        if (obf) Cb[(row + r) * N + col] = f2bf(v);
        else     Cf[(row + r) * N + col] = v;
      }
    }
  }
}

// --------------------------------------------------- causal flash attention (split-K)
// 128-row Q tiles (2 row-frags/wave), 64-key tiles, chunks of CH=4 (2304 blocks
// -> backfill through occupancy decay). Fixed-m softmax p = 2^s.
__global__ __launch_bounds__(256) void flash_attn(
    const us* __restrict__ Kbuf, const us* __restrict__ VT,
    const us* __restrict__ Q,
    float* __restrict__ Oacc, float* __restrict__ Lacc)
{
  __shared__ us Ks[64 * 72];
  __shared__ us Vt[64 * 72];
  __shared__ us Ps[4][32 * 72];

  int lin = blockIdx.x;
  int qt = 15, nc = 0;
  for (; qt >= 0; --qt) { nc = (2 * qt + 5) >> 2; if (lin < nc) break; lin -= nc; }
  const int kt0 = lin * CH;
  const int kt1 = min(kt0 + CH, 2 * qt + 2);

  const int h   = blockIdx.y;
  const int bb  = blockIdx.z;
  const int tid = threadIdx.x;
  const int lane = tid & 63;
  const int wave = tid >> 6;
  const int n16 = lane & 15;
  const int quad = lane >> 4;
  const int qbase = qt * 128;
  const long rowQ0 = (long)bb * SEQ;

  bf16x8 aq[2][2];
#pragma unroll
  for (int rg = 0; rg < 2; rg++) {
    const long gq = (rowQ0 + qbase + wave * 32 + rg * 16 + n16) * DM + h * DH;
    aq[rg][0] = *(const bf16x8*)(Q + gq + quad * 8);
    aq[rg][1] = *(const bf16x8*)(Q + gq + 32 + quad * 8);
  }

  const f32x4 zero = {0.f, 0.f, 0.f, 0.f};
  f32x4 oacc[2][4];
#pragma unroll
  for (int rg = 0; rg < 2; rg++)
#pragma unroll
    for (int d = 0; d < 4; d++) oacc[rg][d] = zero;
  float rsum[2] = {0.f, 0.f};

  const int kk_key = tid >> 3;
  const int kk_d8  = (tid & 7) * 8;
  const int vd  = tid & 63;
  const int vkb = (tid >> 6) * 8;

  const us* kgb = Kbuf + (rowQ0 + kk_key) * 1024 + h * DH + kk_d8;
  const us* vtb = VT + ((long)bb * 1024 + h * DH + vd) * 2048;

  uint4 kpre0, kpre1, vpre0, vpre1;
  auto loadKV = [&](int kt) {
    const us* kg = kgb + (long)kt * (64 * 1024);
    kpre0 = *(const uint4*)kg;
    kpre1 = *(const uint4*)(kg + 32 * 1024);
    const us* vg = vtb + kt * 64 + vkb;
    vpre0 = *(const uint4*)vg;
    vpre1 = *(const uint4*)(vg + 32);
  };
  loadKV(kt0);

  us* Pw = Ps[wave];
  const int qw = qbase + wave * 32;

  for (int kt = kt0; kt < kt1; kt++) {
    const int kb = kt * 64;
    __syncthreads();
    *(uint4*)(Ks + kk_key * 72 + kk_d8)        = kpre0;
    *(uint4*)(Ks + (kk_key + 32) * 72 + kk_d8) = kpre1;
    *(uint4*)(Vt + vd * 72 + vkb)              = vpre0;
    *(uint4*)(Vt + vd * 72 + vkb + 32)         = vpre1;
    __syncthreads();
    if (kt + 1 < kt1) loadKV(kt + 1);

    if (kb > qw + 31) continue;

    f32x4 sv[2][4];
#pragma unroll
    for (int j = 0; j < 4; j++) {
      const bf16x8 ak0 = *(const bf16x8*)(Ks + (j * 16 + n16) * 72 + quad * 8);
      const bf16x8 ak1 = *(const bf16x8*)(Ks + (j * 16 + n16) * 72 + 32 + quad * 8);
#pragma unroll
      for (int rg = 0; rg < 2; rg++) {
        f32x4 s = zero;
        s = __builtin_amdgcn_mfma_f32_16x16x32_bf16(ak0, aq[rg][0], s, 0, 0, 0);
        s = __builtin_amdgcn_mfma_f32_16x16x32_bf16(ak1, aq[rg][1], s, 0, 0, 0);
        sv[rg][j] = s;
      }
    }

#pragma unroll
    for (int rg = 0; rg < 2; rg++) {
      if (kb + 63 > qw + rg * 16) {
        const int qg = qw + rg * 16 + n16;
#pragma unroll
        for (int j = 0; j < 4; j++) {
          const int kl = kb + j * 16 + quad * 4;
#pragma unroll
          for (int r = 0; r < 4; r++)
            sv[rg][j][r] = (kl + r <= qg) ? sv[rg][j][r] : -1e30f;
        }
      }
#pragma unroll
      for (int j = 0; j < 4; j++) {
        const float p0 = __builtin_amdgcn_exp2f(sv[rg][j][0]);
        const float p1 = __builtin_amdgcn_exp2f(sv[rg][j][1]);
        const float p2 = __builtin_amdgcn_exp2f(sv[rg][j][2]);
        const float p3 = __builtin_amdgcn_exp2f(sv[rg][j][3]);
        rsum[rg] += (p0 + p1) + (p2 + p3);
        us4 pk;
        pk.x = f2bf(p0); pk.y = f2bf(p1); pk.z = f2bf(p2); pk.w = f2bf(p3);
        *(us4*)(Pw + (rg * 16 + n16) * 72 + j * 16 + quad * 4) = pk;
      }
    }
    __asm__ volatile("s_waitcnt lgkmcnt(0)" ::: "memory");

#pragma unroll
    for (int rg = 0; rg < 2; rg++)
#pragma unroll
      for (int kc = 0; kc < 2; kc++) {
        const bf16x8 ap = *(const bf16x8*)(Pw + (rg * 16 + n16) * 72 + kc * 32 + quad * 8);
#pragma unroll
        for (int d = 0; d < 4; d++) {
          const bf16x8 bv = *(const bf16x8*)(Vt + (d * 16 + n16) * 72 + kc * 32 + quad * 8);
          oacc[rg][d] = __builtin_amdgcn_mfma_f32_16x16x32_bf16(ap, bv, oacc[rg][d], 0, 0, 0);
        }
      }
  }

#pragma unroll
  for (int rg = 0; rg < 2; rg++) {
    float rs = rsum[rg];
    rs += __shfl_xor(rs, 16);
    rs += __shfl_xor(rs, 32);
    const long rw0 = rowQ0 + qbase + wave * 32 + rg * 16;
    if (quad == 0)
      atomicAdd(&Lacc[(rw0 + n16) * NHEAD + h], rs);
#pragma unroll
    for (int r = 0; r < 4; r++) {
      float* dst = Oacc + (rw0 + quad * 4 + r) * DM + h * DH + n16;
#pragma unroll
      for (int d = 0; d < 4; d++)
        atomicAdd(dst + d * 16, oacc[rg][d][r]);
    }
  }
}

// -------------------------------------------- combine: obuf = Oacc / l (bf16)
__global__ __launch_bounds__(256) void flash_combine(
    const float* __restrict__ Oacc, const float* __restrict__ Lacc,
    us* __restrict__ O)
{
  __shared__ float invl[NHEAD];
  const long row = blockIdx.x;
  const int tid = threadIdx.x;
  if (tid < NHEAD) invl[tid] = 1.f / Lacc[row * NHEAD + tid];
  __syncthreads();
#pragma unroll
  for (int i = 0; i < 4; i++) {
    const int col = tid + i * 256;
    O[row * DM + col] = f2bf(Oacc[row * DM + col] * invl[col >> 6]);
  }
}

// ------------------------------------------------------------------------- host
extern "C" void kernel_launch(void* const* d_in, const int* in_sizes, int n_in,
                              void* d_out, int out_size, void* d_ws, size_t ws_size,
                              hipStream_t stream) {
  const void* x      = d_in[0];
  const void* Wdq    = d_in[1];
  const void* Wuq    = d_in[2];
  const void* qg     = d_in[3];
  const void* qb     = d_in[4];
  const void* Wdkv   = d_in[5];
  const void* Wukv   = d_in[6];
  const void* kvg    = d_in[7];
  const void* kvb    = d_in[8];
  const void* preqg  = d_in[9];
  const void* preqb  = d_in[10];
  const void* prekvg = d_in[11];
  const void* prekvb = d_in[12];
  const void* wo     = d_in[13];

  char* ws = (char*)d_ws;
  const long MB = 1 << 20;
  int* flag = (int*)ws;
  float* S1q  = (float*)(ws + 4096);                 // 4x4096 floats (zeroed)
  float* S2q  = S1q + 4096;
  float* S1kv = S2q + 4096;
  float* S2kv = S1kv + 4096;
  float* u2q  = S2kv + 4096;                         // written directly
  float* c2q  = u2q + 1024;
  float* u2kv = c2q + 1024;
  float* c2kv = u2kv + 2048;
  const int nz4 = (4 * 4096) / 4;

  us* wdq_t   = (us*)(ws + 1 * MB);
  us* wuq_t   = (us*)(ws + 2 * MB);
  us* wdkv_t  = (us*)(ws + 3 * MB);
  us* wukv_t  = (us*)(ws + 5 * MB);
  us* wo_c    = (us*)(ws + 9 * MB);
  us* xq      = (us*)(ws + 11 * MB);
  us* xkv     = (us*)(ws + 19 * MB);
  float* Oacc = (float*)(ws + 27 * MB);              // 16 MB (zeroed in stage0)
  float* Lacc = (float*)(ws + 43 * MB);              // 256 KB
  us* obuf    = (us*)(ws + 43 * MB + 256 * 1024);
  us* tq_bf   = obuf;                                // overlay: dead before combine
  us* qbuf    = (us*)(ws + 43 * MB + 256 * 1024 + 8 * MB);
  us* tkv_bf  = (us*)(ws + 43 * MB + 256 * 1024 + 16 * MB);
  us* Kbuf    = (us*)(ws + 43 * MB + 256 * 1024 + 24 * MB);
  us* VT      = (us*)(ws + 43 * MB + 256 * 1024 + 32 * MB);

  detect_dtype<<<1, 256, 0, stream>>>((const us*)x, flag, (float4*)S1q, nz4);

  {
    TD t0 = { Wdq,  wdq_t,  1024,  512,  512, 1, nullptr, nullptr, nullptr, nullptr };
    TD t1 = { Wuq,  wuq_t,   512, 1024,  512, 1, qg,  qb,  u2q,  c2q  };
    TD t2 = { Wdkv, wdkv_t, 1024, 1024, 1024, 1, nullptr, nullptr, nullptr, nullptr };
    TD t3 = { Wukv, wukv_t, 1024, 2048, 2048, 1, kvg, kvb, u2kv, c2kv };
    TD t4 = { wo,   wo_c,   1024, 1024, 1024, 0, nullptr, nullptr, nullptr, nullptr };
    const int n4 = (16 * 1024 * 1024 + 256 * 1024) / 16;
    stage0<<<10288, 256, 0, stream>>>(t0, t1, t2, t3, t4,
                                      (float4*)Oacc, n4,
                                      x, preqg, preqb, prekvg, prekvb, xq, xkv, flag);
  }

  // down-projection pair: bf16 out + row stats (64x128 tiles)
  {
    GD g0 = { xq,  wdq_t,  tq_bf,   512, 1024, 2, 1.f, 4, S1q,  S2q,  nullptr, nullptr, nullptr };
    GD g1 = { xkv, wdkv_t, tkv_bf, 1024, 1024, 3, 1.f, 4, S1kv, S2kv, nullptr, nullptr, nullptr };
    gemm_mt<<<768, 256, 0, stream>>>(g0, g1, 256, flag);
  }

  // up-projection pair with LN folded; Q scale = (1/8)*log2e
  {
    GD g0 = { tq_bf,  wuq_t,  qbuf, 1024,  512, 3, 0.125f * 1.44269504f, 5,
              S1q,  S2q,  u2q,  c2q,  nullptr };
    GD g1 = { tkv_bf, wukv_t, Kbuf, 2048, 1024, 4, 1.f, 6,
              S1kv, S2kv, u2kv, c2kv, VT };
    gemm_mt<<<1536, 256, 0, stream>>>(g0, g1, 512, flag);
  }

  // flash: grid.x = sum over qt=0..15 of ceil((2qt+2)/4) = 72
  flash_attn<<<dim3(72, NHEAD, BATCH), 256, 0, stream>>>(Kbuf, VT, qbuf, Oacc, Lacc);
  flash_combine<<<NROWS, 256, 0, stream>>>(Oacc, Lacc, obuf);

  // out = O @ wo^T
  {
    GD g0 = { obuf, wo_c, d_out, 1024, 1024, 3, 1.f, 2,
              nullptr, nullptr, nullptr, nullptr, nullptr };
    gemm_mt<<<512, 256, 0, stream>>>(g0, g0, 512, flag);
  }
}

// Round 9
// 281.625 us; speedup vs baseline: 1.0960x; 1.0960x over previous
//
#include <hip/hip_runtime.h>
#include <hip/hip_bf16.h>

#define SEQ   2048
#define BATCH 2
#define NROWS 4096
#define DM    1024
#define NHEAD 16
#define DH    64
#define QP    512
#define KVP   1024
#define CH    8      // key-tiles (of 64) per flash chunk

typedef unsigned short us;
typedef ushort4 us4;
using bf16x8 = __attribute__((ext_vector_type(8))) __bf16;
using f32x4  = __attribute__((ext_vector_type(4))) float;

__device__ __forceinline__ us f2bf(float f) {
  union { float f; unsigned u; } c; c.f = f;
  return (us)((c.u + 0x8000u) >> 16);    // add-round: <=1 ULP, 2 VALU
}
__device__ __forceinline__ float bf2f(us u) {
  union { unsigned u32; float f; } cv;
  cv.u32 = ((unsigned)u) << 16;
  return cv.f;
}
__device__ __forceinline__ float loadp(const void* p, long i, int isbf) {
  return isbf ? bf2f(((const us*)p)[i]) : ((const float*)p)[i];
}
__device__ __forceinline__ void async16(const void* g, void* l) {
  __builtin_amdgcn_global_load_lds((__attribute__((address_space(1))) void*)g,
                                   (__attribute__((address_space(3))) void*)l,
                                   16, 0, 0);
}
__device__ __forceinline__ int nchunks(int qt) { return ((2 * qt + 1) >> 3) + 1; }

// ----------------------------------- dtype probe + zero small atomic buffers
__global__ void detect_dtype(const us* __restrict__ xu, int* __restrict__ flag,
                             float4* __restrict__ zsmall, int nz4) {
  __shared__ int red[256];
  const int tid = threadIdx.x;
  const float4 z = {0.f, 0.f, 0.f, 0.f};
  for (int i = tid; i < nz4; i += 256) zsmall[i] = z;
  int cnt = 0;
  for (int i = tid; i < 4096; i += 256) {
    const int e = (xu[i] >> 7) & 0xff;
    if (e == 0 || (e >= 100 && e <= 134)) cnt++;
  }
  red[tid] = cnt;
  __syncthreads();
  for (int s = 128; s; s >>= 1) {
    if (tid < s) red[tid] += red[tid + s];
    __syncthreads();
  }
  if (tid == 0) *flag = (red[0] >= 3900) ? 1 : 0;
}

// stage0 grid: [0,48) u/c fold vectors; [48,5168) weight prep; [5168,9264) dual-LN.
struct TD { const void* in; us* out; int R, C, nt, trans;
            const void* g; const void* b; float* u; float* c; };

__global__ __launch_bounds__(256) void stage0(
    TD t0, TD t1, TD t2, TD t3, TD t4,
    const void* __restrict__ xin,
    const void* __restrict__ g1, const void* __restrict__ b1,
    const void* __restrict__ g2, const void* __restrict__ b2,
    us* __restrict__ out1, us* __restrict__ out2,
    const int* __restrict__ flag)
{
  __shared__ us tile[32][33];
  __shared__ float red[8];
  __shared__ float musd[2];
  __shared__ float ucred[2][4][64];
  const int tid = threadIdx.x;
  const int isbf = *flag;
  int lin = blockIdx.x;

  if (lin < 48) {                                    // ---- u/c fold vectors
    TD t = (lin < 16) ? t1 : t3;
    const int blk = (lin < 16) ? lin : lin - 16;
    const int Cr = t.R;
    const int Nc = t.C;
    const int colx = tid & 63, cseg = tid >> 6;
    const int col = blk * 64 + colx;
    const int rows = Cr >> 2;
    const int r0 = cseg * rows;
    float usum = 0.f, csum = 0.f;
    for (int cc = 0; cc < rows; cc += 8) {
#pragma unroll
      for (int k = 0; k < 8; k++) {
        const long rr = r0 + cc + k;
        const float w = loadp(t.in, rr * Nc + col, isbf);
        usum += loadp(t.g, rr, isbf) * w;
        csum += loadp(t.b, rr, isbf) * w;
      }
    }
    ucred[0][cseg][colx] = usum;
    ucred[1][cseg][colx] = csum;
    __syncthreads();
    if (tid < 64)
      t.u[blk * 64 + tid] = ucred[0][0][tid] + ucred[0][1][tid] + ucred[0][2][tid] + ucred[0][3][tid];
    else if (tid < 128) {
      const int tt = tid - 64;
      t.c[blk * 64 + tt] = ucred[1][0][tt] + ucred[1][1][tt] + ucred[1][2][tt] + ucred[1][3][tt];
    }
    return;
  }
  lin -= 48;
  if (lin < 5120) {                                  // ---- weight prep
    TD t = t0;
    if (lin >= t.nt) { lin -= t.nt; t = t1;
      if (lin >= t.nt) { lin -= t.nt; t = t2;
        if (lin >= t.nt) { lin -= t.nt; t = t3;
          if (lin >= t.nt) { lin -= t.nt; t = t4; } } } }
    const int ntx = t.C >> 5;
    const int by = lin / ntx, bx = lin - by * ntx;
    const int tx = tid & 31, ty = tid >> 5;
    const long r0 = (long)by * 32, c0 = (long)bx * 32;
    if (t.trans) {
#pragma unroll
      for (int i = 0; i < 32; i += 8)
        tile[ty + i][tx] = isbf ? ((const us*)t.in)[(r0 + ty + i) * t.C + c0 + tx]
                                : f2bf(((const float*)t.in)[(r0 + ty + i) * t.C + c0 + tx]);
      __syncthreads();
      if (t.g) {
        const float gw = loadp(t.g, r0 + tx, isbf);
#pragma unroll
        for (int i = 0; i < 32; i += 8)
          t.out[(c0 + ty + i) * t.R + r0 + tx] = f2bf(bf2f(tile[tx][ty + i]) * gw);
      } else {
#pragma unroll
        for (int i = 0; i < 32; i += 8)
          t.out[(c0 + ty + i) * t.R + r0 + tx] = tile[tx][ty + i];
      }
    } else {
#pragma unroll
      for (int i = 0; i < 32; i += 8)
        t.out[(r0 + ty + i) * t.C + c0 + tx] =
            isbf ? ((const us*)t.in)[(r0 + ty + i) * t.C + c0 + tx]
                 : f2bf(((const float*)t.in)[(r0 + ty + i) * t.C + c0 + tx]);
    }
    return;
  }
  // ---- dual LayerNorm row of x
  const long row = lin - 5120;
  float v[4];
  float s = 0.f, s2 = 0.f;
#pragma unroll
  for (int i = 0; i < 4; i++) {
    const long c = tid + i * 256;
    const float t = loadp(xin, row * 1024 + c, isbf);
    v[i] = t; s += t; s2 += t * t;
  }
#pragma unroll
  for (int off = 32; off > 0; off >>= 1) {
    s  += __shfl_down(s,  off);
    s2 += __shfl_down(s2, off);
  }
  const int wave = tid >> 6, lane = tid & 63;
  if (lane == 0) { red[wave] = s; red[4 + wave] = s2; }
  __syncthreads();
  if (tid == 0) {
    const float ts = red[0] + red[1] + red[2] + red[3];
    const float t2 = red[4] + red[5] + red[6] + red[7];
    const float mu = ts * (1.f / 1024.f);
    const float var = t2 * (1.f / 1024.f) - mu * mu;
    musd[0] = mu; musd[1] = rsqrtf(var + 1e-5f);
  }
  __syncthreads();
  const float mu = musd[0], rs = musd[1];
#pragma unroll
  for (int i = 0; i < 4; i++) {
    const long c = tid + i * 256;
    const float nrm = (v[i] - mu) * rs;
    out1[row * 1024 + c] = f2bf(nrm * loadp(g1, c, isbf) + loadp(b1, c, isbf));
    out2[row * 1024 + c] = f2bf(nrm * loadp(g2, c, isbf) + loadp(b2, c, isbf));
  }
}

// ------------------------------------------------------------------ GEMM C = A @ B
// 64x128 tile, BK=64 as two 32-slices. A [M,K] bf16, Bt [N,K] bf16, C [M,N].
// omode: 1 bf16; 2 bf16 iff *flag else fp32; 4 bf16 + row stats atomics;
//        5 LN-fold epilogue; 6 LN-fold + kv split (K->C stride 1024, V->C2^T).
struct GD { const us* A; const us* Bt; void* C; int N, K, nxs; float scale; int omode;
            float* S1; float* S2; const float* u; const float* cv; us* C2; };

__global__ __launch_bounds__(256) void gemm_mt(GD g0, GD g1, int nb0,
                                               const int* __restrict__ flag) {
  __shared__ us As[2][64 * 32];
  __shared__ us Bs[2][128 * 32];
  GD g;
  int lin = blockIdx.x;
  if (lin < nb0) g = g0; else { g = g1; lin -= nb0; }
  const int by = lin >> g.nxs;
  const int bx = lin - (by << g.nxs);
  const int N = g.N, K = g.K;

  const int tid  = threadIdx.x;
  const int lane = tid & 63;
  const int wave = tid >> 6;
  const int n16  = lane & 15;
  const int quad = lane >> 4;
  const long m0 = (long)by * 64;
  const long n0 = (long)bx * 128;
  const int wm = (wave >> 1) * 32;
  const int wn = (wave & 1) * 64;

  const f32x4 zero = {0.f, 0.f, 0.f, 0.f};
  f32x4 acc[2][4];
#pragma unroll
  for (int i = 0; i < 2; i++)
#pragma unroll
    for (int j = 0; j < 4; j++) acc[i][j] = zero;

  const int srow = tid >> 2;
  const int scol = (tid & 3) * 8;
  const us* Ag  = g.A  + (m0 + srow) * K + scol;
  const us* Bg0 = g.Bt + (n0 + srow) * K + scol;
  const us* Bg1 = g.Bt + (n0 + 64 + srow) * K + scol;
  const int lds_off = srow * 32 + scol;

  for (int k0 = 0; k0 < K; k0 += 64) {
#pragma unroll
    for (int s = 0; s < 2; s++) {
      const int ks = k0 + s * 32;
      async16(Ag  + ks, As[s] + lds_off);
      async16(Bg0 + ks, Bs[s] + lds_off);
      async16(Bg1 + ks, Bs[s] + 2048 + lds_off);
    }
    __syncthreads();
#pragma unroll
    for (int s = 0; s < 2; s++) {
      bf16x8 af[2], bfv[4];
#pragma unroll
      for (int i = 0; i < 2; i++)
        af[i] = *(const bf16x8*)(As[s] + (wm + i * 16 + n16) * 32 + quad * 8);
#pragma unroll
      for (int j = 0; j < 4; j++)
        bfv[j] = *(const bf16x8*)(Bs[s] + (wn + j * 16 + n16) * 32 + quad * 8);
#pragma unroll
      for (int i = 0; i < 2; i++)
#pragma unroll
        for (int j = 0; j < 4; j++)
          acc[i][j] = __builtin_amdgcn_mfma_f32_16x16x32_bf16(af[i], bfv[j], acc[i][j], 0, 0, 0);
    }
    __syncthreads();
  }

  const int om = g.omode;
  us* Cb = (us*)g.C;

  if (om == 4) {
    float s1a[2][4], s2a[2][4];
#pragma unroll
    for (int i = 0; i < 2; i++)
#pragma unroll
      for (int r = 0; r < 4; r++) { s1a[i][r] = 0.f; s2a[i][r] = 0.f; }
#pragma unroll
    for (int i = 0; i < 2; i++) {
      const long row = m0 + wm + i * 16 + quad * 4;
#pragma unroll
      for (int j = 0; j < 4; j++) {
        const long col = n0 + wn + j * 16 + n16;
#pragma unroll
        for (int r = 0; r < 4; r++) {
          const float v = acc[i][j][r] * g.scale;
          Cb[(row + r) * N + col] = f2bf(v);
          s1a[i][r] += v;
          s2a[i][r] += v * v;
        }
      }
    }
#pragma unroll
    for (int i = 0; i < 2; i++)
#pragma unroll
      for (int r = 0; r < 4; r++) {
        float a = s1a[i][r], b = s2a[i][r];
#pragma unroll
        for (int off = 1; off < 16; off <<= 1) {
          a += __shfl_xor(a, off);
          b += __shfl_xor(b, off);
        }
        if (n16 == 0) {
          const long row = m0 + wm + i * 16 + quad * 4 + r;
          atomicAdd(&g.S1[row], a);
          atomicAdd(&g.S2[row], b);
        }
      }
    return;
  }

  if (om == 5 || om == 6) {
    const float invK = 1.f / (float)K;
    float rsr[2][4], mur[2][4];
#pragma unroll
    for (int i = 0; i < 2; i++) {
      const long row = m0 + wm + i * 16 + quad * 4;
#pragma unroll
      for (int r = 0; r < 4; r++) {
        const float s1 = g.S1[row + r];
        const float s2 = g.S2[row + r];
        const float mu = s1 * invK;
        const float var = s2 * invK - mu * mu;
        const float rs = rsqrtf(var + 1e-5f);
        rsr[i][r] = rs;
        mur[i][r] = mu * rs;
      }
    }
    const bool vhalf = (om == 6) && (n0 >= 1024);
#pragma unroll
    for (int i = 0; i < 2; i++) {
      const long rowb = m0 + wm + i * 16 + quad * 4;
#pragma unroll
      for (int j = 0; j < 4; j++) {
        const long col = n0 + wn + j * 16 + n16;
        const float uu = g.u[col];
        const float cc = g.cv[col];
        if (!vhalf) {
          const int nst = (om == 6) ? 1024 : N;
#pragma unroll
          for (int r = 0; r < 4; r++) {
            const float v = g.scale * (rsr[i][r] * acc[i][j][r] - mur[i][r] * uu + cc);
            Cb[(rowb + r) * nst + col] = f2bf(v);
          }
        } else {
          const int bbq = (int)(rowb >> 11);
          const int key = (int)(rowb & 2047);
          const int dimg = (int)col - 1024;
          us4 pk;
          pk.x = f2bf(g.scale * (rsr[i][0] * acc[i][j][0] - mur[i][0] * uu + cc));
          pk.y = f2bf(g.scale * (rsr[i][1] * acc[i][j][1] - mur[i][1] * uu + cc));
          pk.z = f2bf(g.scale * (rsr[i][2] * acc[i][j][2] - mur[i][2] * uu + cc));
          pk.w = f2bf(g.scale * (rsr[i][3] * acc[i][j][3] - mur[i][3] * uu + cc));
          *(us4*)(g.C2 + ((long)(bbq * 1024 + dimg)) * 2048 + key) = pk;
        }
      }
    }
    return;
  }

  const bool obf = (om == 1) || (om == 2 && *flag != 0);
  float* Cf = (float*)g.C;
#pragma unroll
  for (int i = 0; i < 2; i++) {
    const long row = m0 + wm + i * 16 + quad * 4;
#pragma unroll
    for (int j = 0; j < 4; j++) {
      const long col = n0 + wn + j * 16 + n16;
#pragma unroll
      for (int r = 0; r < 4; r++) {
        const float v = acc[i][j][r] * g.scale;
        if (obf) Cb[(row + r) * N + col] = f2bf(v);
        else     Cf[(row + r) * N + col] = v;
      }
    }
  }
}

// --------------------------------------------------- causal flash attention (split-K)
// ATOMIC-FREE partials: each block owns slot (g,h,bb) and plain-stores its
// partial O (128x64 f32) + partial l (128 f32). R8 showed the atomicAdd
// epilogue was ~65% of flash time (dur tracked lane-atomic count superlinearly).
// 1-D grid 1280; g = idx>>5 (qt descending -> long chains dispatch first).
__global__ __launch_bounds__(256) void flash_attn(
    const us* __restrict__ Kbuf, const us* __restrict__ VT,
    const us* __restrict__ Q,
    float* __restrict__ Opart, float* __restrict__ Lpart)
{
  __shared__ us Ks[64 * 72];
  __shared__ us Vt[64 * 72];
  __shared__ us Ps[4][32 * 72];

  const int gidx = blockIdx.x >> 5;
  const int hb   = blockIdx.x & 31;
  const int h    = hb >> 1;
  const int bb   = hb & 1;

  int lin = gidx;
  int qt = 15, nc = 0;
  for (; qt >= 0; --qt) { nc = nchunks(qt); if (lin < nc) break; lin -= nc; }
  const int kt0 = lin * CH;
  const int kt1 = min(kt0 + CH, 2 * qt + 2);

  const int tid = threadIdx.x;
  const int lane = tid & 63;
  const int wave = tid >> 6;
  const int n16 = lane & 15;
  const int quad = lane >> 4;
  const int qbase = qt * 128;
  const long rowQ0 = (long)bb * SEQ;

  bf16x8 aq[2][2];
#pragma unroll
  for (int rg = 0; rg < 2; rg++) {
    const long gq = (rowQ0 + qbase + wave * 32 + rg * 16 + n16) * DM + h * DH;
    aq[rg][0] = *(const bf16x8*)(Q + gq + quad * 8);
    aq[rg][1] = *(const bf16x8*)(Q + gq + 32 + quad * 8);
  }

  const f32x4 zero = {0.f, 0.f, 0.f, 0.f};
  f32x4 oacc[2][4];
#pragma unroll
  for (int rg = 0; rg < 2; rg++)
#pragma unroll
    for (int d = 0; d < 4; d++) oacc[rg][d] = zero;
  float rsum[2] = {0.f, 0.f};

  const int kk_key = tid >> 3;
  const int kk_d8  = (tid & 7) * 8;
  const int vd  = tid & 63;
  const int vkb = (tid >> 6) * 8;

  const us* kgb = Kbuf + (rowQ0 + kk_key) * 1024 + h * DH + kk_d8;
  const us* vtb = VT + ((long)bb * 1024 + h * DH + vd) * 2048;

  uint4 kpre0, kpre1, vpre0, vpre1;
  auto loadKV = [&](int kt) {
    const us* kg = kgb + (long)kt * (64 * 1024);
    kpre0 = *(const uint4*)kg;
    kpre1 = *(const uint4*)(kg + 32 * 1024);
    const us* vg = vtb + kt * 64 + vkb;
    vpre0 = *(const uint4*)vg;
    vpre1 = *(const uint4*)(vg + 32);
  };
  loadKV(kt0);

  us* Pw = Ps[wave];
  const int qw = qbase + wave * 32;

  for (int kt = kt0; kt < kt1; kt++) {
    const int kb = kt * 64;
    __syncthreads();
    *(uint4*)(Ks + kk_key * 72 + kk_d8)        = kpre0;
    *(uint4*)(Ks + (kk_key + 32) * 72 + kk_d8) = kpre1;
    *(uint4*)(Vt + vd * 72 + vkb)              = vpre0;
    *(uint4*)(Vt + vd * 72 + vkb + 32)         = vpre1;
    __syncthreads();
    if (kt + 1 < kt1) loadKV(kt + 1);

    if (kb > qw + 31) continue;

    f32x4 sv[2][4];
#pragma unroll
    for (int j = 0; j < 4; j++) {
      const bf16x8 ak0 = *(const bf16x8*)(Ks + (j * 16 + n16) * 72 + quad * 8);
      const bf16x8 ak1 = *(const bf16x8*)(Ks + (j * 16 + n16) * 72 + 32 + quad * 8);
#pragma unroll
      for (int rg = 0; rg < 2; rg++) {
        f32x4 s = zero;
        s = __builtin_amdgcn_mfma_f32_16x16x32_bf16(ak0, aq[rg][0], s, 0, 0, 0);
        s = __builtin_amdgcn_mfma_f32_16x16x32_bf16(ak1, aq[rg][1], s, 0, 0, 0);
        sv[rg][j] = s;
      }
    }

#pragma unroll
    for (int rg = 0; rg < 2; rg++) {
      if (kb + 63 > qw + rg * 16) {
        const int qg = qw + rg * 16 + n16;
#pragma unroll
        for (int j = 0; j < 4; j++) {
          const int kl = kb + j * 16 + quad * 4;
#pragma unroll
          for (int r = 0; r < 4; r++)
            sv[rg][j][r] = (kl + r <= qg) ? sv[rg][j][r] : -1e30f;
        }
      }
#pragma unroll
      for (int j = 0; j < 4; j++) {
        const float p0 = __builtin_amdgcn_exp2f(sv[rg][j][0]);
        const float p1 = __builtin_amdgcn_exp2f(sv[rg][j][1]);
        const float p2 = __builtin_amdgcn_exp2f(sv[rg][j][2]);
        const float p3 = __builtin_amdgcn_exp2f(sv[rg][j][3]);
        rsum[rg] += (p0 + p1) + (p2 + p3);
        us4 pk;
        pk.x = f2bf(p0); pk.y = f2bf(p1); pk.z = f2bf(p2); pk.w = f2bf(p3);
        *(us4*)(Pw + (rg * 16 + n16) * 72 + j * 16 + quad * 4) = pk;
      }
    }
    __asm__ volatile("s_waitcnt lgkmcnt(0)" ::: "memory");

#pragma unroll
    for (int rg = 0; rg < 2; rg++)
#pragma unroll
      for (int kc = 0; kc < 2; kc++) {
        const bf16x8 ap = *(const bf16x8*)(Pw + (rg * 16 + n16) * 72 + kc * 32 + quad * 8);
#pragma unroll
        for (int d = 0; d < 4; d++) {
          const bf16x8 bv = *(const bf16x8*)(Vt + (d * 16 + n16) * 72 + kc * 32 + quad * 8);
          oacc[rg][d] = __builtin_amdgcn_mfma_f32_16x16x32_bf16(ap, bv, oacc[rg][d], 0, 0, 0);
        }
      }
  }

  // epilogue: plain stores into this block's private slot
  const long slot = ((long)gidx * 16 + h) * 2 + bb;
  float* Op = Opart + slot * (128 * 64);
  float* Lp = Lpart + slot * 128;
#pragma unroll
  for (int rg = 0; rg < 2; rg++) {
    float rs = rsum[rg];
    rs += __shfl_xor(rs, 16);
    rs += __shfl_xor(rs, 32);
    const int lr0 = wave * 32 + rg * 16;
    if (quad == 0) Lp[lr0 + n16] = rs;
#pragma unroll
    for (int r = 0; r < 4; r++) {
      float* dst = Op + (lr0 + quad * 4 + r) * 64 + n16;
#pragma unroll
      for (int d = 0; d < 4; d++)
        dst[d * 16] = oacc[rg][d][r];
    }
  }
}

// ------------------- combine: obuf[row] = sum_c Opart / sum_c Lpart (bf16)
__global__ __launch_bounds__(256) void flash_combine(
    const float* __restrict__ Opart, const float* __restrict__ Lpart,
    us* __restrict__ O)
{
  const int row = blockIdx.x;
  const int bb = row >> 11;
  const int r2 = row & 2047;
  const int qt = r2 >> 7;
  const int lr = r2 & 127;
  const int tid = threadIdx.x;

  int base = 0;
  for (int q = qt + 1; q <= 15; q++) base += nchunks(q);
  const int ncq = nchunks(qt);

#pragma unroll
  for (int i = 0; i < 4; i++) {
    const int col = tid + i * 256;
    const int h = col >> 6;
    const int d = col & 63;
    float osum = 0.f, lsum = 0.f;
    for (int c = 0; c < ncq; c++) {
      const long slot = ((long)(base + c) * 16 + h) * 2 + bb;
      osum += Opart[slot * (128 * 64) + lr * 64 + d];
      lsum += Lpart[slot * 128 + lr];
    }
    O[(long)row * DM + col] = f2bf(osum / lsum);
  }
}

// ------------------------------------------------------------------------- host
extern "C" void kernel_launch(void* const* d_in, const int* in_sizes, int n_in,
                              void* d_out, int out_size, void* d_ws, size_t ws_size,
                              hipStream_t stream) {
  const void* x      = d_in[0];
  const void* Wdq    = d_in[1];
  const void* Wuq    = d_in[2];
  const void* qg     = d_in[3];
  const void* qb     = d_in[4];
  const void* Wdkv   = d_in[5];
  const void* Wukv   = d_in[6];
  const void* kvg    = d_in[7];
  const void* kvb    = d_in[8];
  const void* preqg  = d_in[9];
  const void* preqb  = d_in[10];
  const void* prekvg = d_in[11];
  const void* prekvb = d_in[12];
  const void* wo     = d_in[13];

  char* ws = (char*)d_ws;
  const long MB = 1 << 20;
  const long KB = 1 << 10;
  int* flag = (int*)ws;
  float* S1q  = (float*)(ws + 4096);                 // 4x4096 floats (zeroed)
  float* S2q  = S1q + 4096;
  float* S1kv = S2q + 4096;
  float* S2kv = S1kv + 4096;
  float* u2q  = S2kv + 4096;
  float* c2q  = u2q + 1024;
  float* u2kv = c2q + 1024;
  float* c2kv = u2kv + 2048;
  const int nz4 = (4 * 4096) / 4;

  us* wdq_t   = (us*)(ws + 1 * MB);
  us* wuq_t   = (us*)(ws + 2 * MB);
  us* wdkv_t  = (us*)(ws + 3 * MB);
  us* wukv_t  = (us*)(ws + 5 * MB);
  us* wo_c    = (us*)(ws + 9 * MB);
  us* xq      = (us*)(ws + 11 * MB);                 // 8 MB  [dead after down-GEMM]
  us* xkv     = (us*)(ws + 19 * MB);                 // 8 MB  [dead after down-GEMM]
  us* tq_bf   = (us*)(ws + 27 * MB);                 // 4 MB  [dead after up-GEMM]
  us* tkv_bf  = (us*)(ws + 31 * MB);                 // 8 MB  [dead after up-GEMM]
  // Opart overlays xq/xkv/tq/tkv (all dead before flash writes it):
  float* Opart = (float*)(ws + 11 * MB);             // 1280 slots x 32 KB = 40 MB -> ends 51 MB
  float* Lpart = (float*)(ws + 51 * MB);             // 640 KB
  us* qbuf    = (us*)(ws + 51 * MB + 640 * KB);      // 8 MB  [dead after flash]
  us* obuf    = qbuf;                                // overlay: written by combine
  us* Kbuf    = (us*)(ws + 59 * MB + 640 * KB);      // 8 MB
  us* VT      = (us*)(ws + 67 * MB + 640 * KB);      // 8 MB -> ends ~75.6 MB

  detect_dtype<<<1, 256, 0, stream>>>((const us*)x, flag, (float4*)S1q, nz4);

  {
    TD t0 = { Wdq,  wdq_t,  1024,  512,  512, 1, nullptr, nullptr, nullptr, nullptr };
    TD t1 = { Wuq,  wuq_t,   512, 1024,  512, 1, qg,  qb,  u2q,  c2q  };
    TD t2 = { Wdkv, wdkv_t, 1024, 1024, 1024, 1, nullptr, nullptr, nullptr, nullptr };
    TD t3 = { Wukv, wukv_t, 1024, 2048, 2048, 1, kvg, kvb, u2kv, c2kv };
    TD t4 = { wo,   wo_c,   1024, 1024, 1024, 0, nullptr, nullptr, nullptr, nullptr };
    stage0<<<9264, 256, 0, stream>>>(t0, t1, t2, t3, t4,
                                     x, preqg, preqb, prekvg, prekvb, xq, xkv, flag);
  }

  // down-projection pair: bf16 out + row stats (64x128 tiles)
  {
    GD g0 = { xq,  wdq_t,  tq_bf,   512, 1024, 2, 1.f, 4, S1q,  S2q,  nullptr, nullptr, nullptr };
    GD g1 = { xkv, wdkv_t, tkv_bf, 1024, 1024, 3, 1.f, 4, S1kv, S2kv, nullptr, nullptr, nullptr };
    gemm_mt<<<768, 256, 0, stream>>>(g0, g1, 256, flag);
  }

  // up-projection pair with LN folded; Q scale = (1/8)*log2e
  {
    GD g0 = { tq_bf,  wuq_t,  qbuf, 1024,  512, 3, 0.125f * 1.44269504f, 5,
              S1q,  S2q,  u2q,  c2q,  nullptr };
    GD g1 = { tkv_bf, wukv_t, Kbuf, 2048, 1024, 4, 1.f, 6,
              S1kv, S2kv, u2kv, c2kv, VT };
    gemm_mt<<<1536, 256, 0, stream>>>(g0, g1, 512, flag);
  }

  // flash: 1-D grid = 40 chunks x 32 (h,bb)
  flash_attn<<<1280, 256, 0, stream>>>(Kbuf, VT, qbuf, Opart, Lpart);
  flash_combine<<<NROWS, 256, 0, stream>>>(Opart, Lpart, obuf);

  // out = O @ wo^T
  {
    GD g0 = { obuf, wo_c, d_out, 1024, 1024, 3, 1.f, 2,
              nullptr, nullptr, nullptr, nullptr, nullptr };
    gemm_mt<<<512, 256, 0, stream>>>(g0, g0, 512, flag);
  }
}